// Round 1
// baseline (2533.252 us; speedup 1.0000x reference)
//
#include <hip/hip_runtime.h>
#include <hip/hip_bf16.h>

// ---------------------------------------------------------------------------
// GAT 2-layer forward for N=50000 nodes, E=800000 edges (+N self loops).
// Layer1: in=128, H=4, C=32, concat -> [N,128], +bias1, ReLU
// Layer2: in=128, H=1, C=64, mean(1 head)=identity -> [N,64], +bias2
// Softmax over incoming edges per dst node; max-subtraction skipped (scores
// are O(1), exp() safe in fp32; mathematically identical alphas).
// ---------------------------------------------------------------------------

#define TS 64
#define KT 16

// C[N][M] = A[N][128] @ B[128][M], M multiple of 64 (via grid.y)
__global__ __launch_bounds__(256) void gemm_k128(
    const float* __restrict__ A, const float* __restrict__ B,
    float* __restrict__ C, int N, int M) {
  __shared__ float As[KT][TS];  // As[k][row]
  __shared__ float Bs[KT][TS];  // Bs[k][col]
  const int K = 128;
  int tid = threadIdx.x;
  int tx = tid & 15, ty = tid >> 4;
  int rowBase = blockIdx.x * TS;
  int colBase = blockIdx.y * TS;
  float acc[4][4];
#pragma unroll
  for (int i = 0; i < 4; i++)
#pragma unroll
    for (int j = 0; j < 4; j++) acc[i][j] = 0.f;

  for (int k0 = 0; k0 < K; k0 += KT) {
    // stage A tile (64 rows x 16 k), transposed into As[k][row]
    {
      int r = tid >> 2;            // 0..63
      int kc = (tid & 3) << 2;     // 0,4,8,12
      int row = rowBase + r;
      float4 av = make_float4(0.f, 0.f, 0.f, 0.f);
      if (row < N) av = *(const float4*)(A + (size_t)row * K + k0 + kc);
      As[kc + 0][r] = av.x;
      As[kc + 1][r] = av.y;
      As[kc + 2][r] = av.z;
      As[kc + 3][r] = av.w;
    }
    // stage B tile (16 k x 64 cols)
    {
      int kk = tid >> 4;           // 0..15
      int cc = (tid & 15) << 2;    // 0..60
      *(float4*)&Bs[kk][cc] = *(const float4*)(B + (size_t)(k0 + kk) * M + colBase + cc);
    }
    __syncthreads();
#pragma unroll
    for (int kk = 0; kk < KT; ++kk) {
      float4 a4 = *(const float4*)&As[kk][ty << 2];
      float4 b4 = *(const float4*)&Bs[kk][tx << 2];
      float aa[4] = {a4.x, a4.y, a4.z, a4.w};
      float bb[4] = {b4.x, b4.y, b4.z, b4.w};
#pragma unroll
      for (int i = 0; i < 4; i++)
#pragma unroll
        for (int j = 0; j < 4; j++) acc[i][j] = fmaf(aa[i], bb[j], acc[i][j]);
    }
    __syncthreads();
  }
#pragma unroll
  for (int i = 0; i < 4; i++) {
    int row = rowBase + (ty << 2) + i;
    if (row < N) {
      float4 v = make_float4(acc[i][0], acc[i][1], acc[i][2], acc[i][3]);
      *(float4*)(C + (size_t)row * M + colBase + (tx << 2)) = v;
    }
  }
}

// per-(node,head) attention scores: s = <h[n,h,:], a[h,:]>
__global__ void att_scores(const float* __restrict__ h,
                           const float* __restrict__ a_src,
                           const float* __restrict__ a_dst,
                           float* __restrict__ ssrc, float* __restrict__ sdst,
                           int N, int H, int C) {
  int idx = blockIdx.x * blockDim.x + threadIdx.x;
  if (idx >= N * H) return;
  int n = idx / H, hh = idx % H;
  const float* hp = h + (size_t)n * H * C + (size_t)hh * C;
  const float* as = a_src + hh * C;
  const float* ad = a_dst + hh * C;
  float s1 = 0.f, s2 = 0.f;
  for (int c = 0; c < C; ++c) {
    float v = hp[c];
    s1 = fmaf(v, as[c], s1);
    s2 = fmaf(v, ad[c], s2);
  }
  ssrc[idx] = s1;
  sdst[idx] = s2;
}

// edge pass A: denom[dst,h] += exp(lrelu(ssrc[src,h]+sdst[dst,h]))
__global__ void edge_denom(const int* __restrict__ ei, int E, int N,
                           const float* __restrict__ ssrc,
                           const float* __restrict__ sdst,
                           float* __restrict__ denom, int H) {
  int e = blockIdx.x * blockDim.x + threadIdx.x;
  int ET = E + N;
  if (e >= ET) return;
  int s, d;
  if (e < E) {
    s = ei[e];
    d = ei[E + e];
  } else {
    s = e - E;
    d = s;
  }
  for (int hh = 0; hh < H; ++hh) {
    float sc = ssrc[s * H + hh] + sdst[d * H + hh];
    sc = sc > 0.f ? sc : 0.2f * sc;
    atomicAdd(denom + d * H + hh, expf(sc));
  }
}

// edge pass B: out[dst,c] += alpha(e,h) * h[src,c]; one thread = 4 channels
template <int H, int C>
__global__ void edge_aggr(const int* __restrict__ ei, int E, int N,
                          const float* __restrict__ h,
                          const float* __restrict__ ssrc,
                          const float* __restrict__ sdst,
                          const float* __restrict__ denom,
                          float* __restrict__ out) {
  const int G = (H * C) / 4;  // float4 groups per edge
  long idx = (long)blockIdx.x * blockDim.x + threadIdx.x;
  long total = (long)(E + N) * G;
  if (idx >= total) return;
  int e = (int)(idx / G);
  int g = (int)(idx % G);
  int c4 = g * 4;
  int hh = c4 / C;
  int s, d;
  if (e < E) {
    s = ei[e];
    d = ei[E + e];
  } else {
    s = e - E;
    d = s;
  }
  float sc = ssrc[s * H + hh] + sdst[d * H + hh];
  sc = sc > 0.f ? sc : 0.2f * sc;
  float w = expf(sc) / denom[d * H + hh];
  float4 hv = *(const float4*)(h + (size_t)s * H * C + c4);
  float* op = out + (size_t)d * H * C + c4;
  atomicAdd(op + 0, w * hv.x);
  atomicAdd(op + 1, w * hv.y);
  atomicAdd(op + 2, w * hv.z);
  atomicAdd(op + 3, w * hv.w);
}

// io[n,c] = (relu?) (io[n,c] + bias[c]); float4 per thread
__global__ void bias_act(float* __restrict__ io, const float* __restrict__ bias,
                         int total, int M, int do_relu) {
  int idx = blockIdx.x * blockDim.x + threadIdx.x;
  int base = idx * 4;
  if (base >= total) return;
  float4 v = *(float4*)(io + base);
  int c = base % M;
  float4 b = *(const float4*)(bias + c);
  v.x += b.x;
  v.y += b.y;
  v.z += b.z;
  v.w += b.w;
  if (do_relu) {
    v.x = fmaxf(v.x, 0.f);
    v.y = fmaxf(v.y, 0.f);
    v.z = fmaxf(v.z, 0.f);
    v.w = fmaxf(v.w, 0.f);
  }
  *(float4*)(io + base) = v;
}

extern "C" void kernel_launch(void* const* d_in, const int* in_sizes, int n_in,
                              void* d_out, int out_size, void* d_ws, size_t ws_size,
                              hipStream_t stream) {
  const float* x   = (const float*)d_in[0];
  const int*   ei  = (const int*)d_in[1];
  const float* W1  = (const float*)d_in[2];
  const float* as1 = (const float*)d_in[3];
  const float* ad1 = (const float*)d_in[4];
  const float* b1  = (const float*)d_in[5];
  const float* W2  = (const float*)d_in[6];
  const float* as2 = (const float*)d_in[7];
  const float* ad2 = (const float*)d_in[8];
  const float* b2  = (const float*)d_in[9];

  const int N = in_sizes[0] / 128;  // 50000
  const int E = in_sizes[1] / 2;    // 800000
  const int ET = E + N;

  float* p = (float*)d_ws;
  float* h1     = p; p += (size_t)N * 128;
  float* ssrc1  = p; p += (size_t)N * 4;
  float* sdst1  = p; p += (size_t)N * 4;
  float* h2     = p; p += (size_t)N * 64;
  float* ssrc2  = p; p += N;
  float* sdst2  = p; p += N;
  // contiguous zero-init region: denom1 | out1 | denom2
  float* denom1 = p; p += (size_t)N * 4;
  float* out1   = p; p += (size_t)N * 128;
  float* denom2 = p; p += N;

  hipMemsetAsync(denom1, 0, ((size_t)N * 4 + (size_t)N * 128 + (size_t)N) * sizeof(float), stream);
  hipMemsetAsync(d_out, 0, (size_t)out_size * sizeof(float), stream);

  dim3 blk(256);

  // ---- layer 1 ----
  gemm_k128<<<dim3((N + TS - 1) / TS, 128 / TS), blk, 0, stream>>>(x, W1, h1, N, 128);
  att_scores<<<dim3((N * 4 + 255) / 256), blk, 0, stream>>>(h1, as1, ad1, ssrc1, sdst1, N, 4, 32);
  edge_denom<<<dim3((ET + 255) / 256), blk, 0, stream>>>(ei, E, N, ssrc1, sdst1, denom1, 4);
  {
    long total = (long)ET * 32;
    edge_aggr<4, 32><<<dim3((unsigned)((total + 255) / 256)), blk, 0, stream>>>(
        ei, E, N, h1, ssrc1, sdst1, denom1, out1);
  }
  bias_act<<<dim3((N * 128 / 4 + 255) / 256), blk, 0, stream>>>(out1, b1, N * 128, 128, 1);

  // ---- layer 2 ----
  gemm_k128<<<dim3((N + TS - 1) / TS, 1), blk, 0, stream>>>(out1, W2, h2, N, 64);
  att_scores<<<dim3((N + 255) / 256), blk, 0, stream>>>(h2, as2, ad2, ssrc2, sdst2, N, 1, 64);
  edge_denom<<<dim3((ET + 255) / 256), blk, 0, stream>>>(ei, E, N, ssrc2, sdst2, denom2, 1);
  {
    long total = (long)ET * 16;
    edge_aggr<1, 64><<<dim3((unsigned)((total + 255) / 256)), blk, 0, stream>>>(
        ei, E, N, h2, ssrc2, sdst2, denom2, (float*)d_out);
  }
  bias_act<<<dim3((out_size / 4 + 255) / 256), blk, 0, stream>>>((float*)d_out, b2, out_size, 64, 0);
}

// Round 2
// 450.680 us; speedup vs baseline: 5.6210x; 5.6210x over previous
//
#include <hip/hip_runtime.h>
#include <hip/hip_bf16.h>

// ---------------------------------------------------------------------------
// GAT 2-layer forward. N=50000 nodes, E=800000 edges (+N self loops).
// Round 2: CSR-based gather aggregation (no float atomics), fused
// softmax-as-weighted-average + bias + activation in the aggregator.
// ---------------------------------------------------------------------------

#define TS 64
#define KT 16

// C[N][M] = A[N][128] @ B[128][M]
__global__ __launch_bounds__(256) void gemm_k128(
    const float* __restrict__ A, const float* __restrict__ B,
    float* __restrict__ C, int N, int M) {
  __shared__ float As[KT][TS];
  __shared__ float Bs[KT][TS];
  const int K = 128;
  int tid = threadIdx.x;
  int tx = tid & 15, ty = tid >> 4;
  int rowBase = blockIdx.x * TS;
  int colBase = blockIdx.y * TS;
  float acc[4][4];
#pragma unroll
  for (int i = 0; i < 4; i++)
#pragma unroll
    for (int j = 0; j < 4; j++) acc[i][j] = 0.f;

  for (int k0 = 0; k0 < K; k0 += KT) {
    {
      int r = tid >> 2;
      int kc = (tid & 3) << 2;
      int row = rowBase + r;
      float4 av = make_float4(0.f, 0.f, 0.f, 0.f);
      if (row < N) av = *(const float4*)(A + (size_t)row * K + k0 + kc);
      As[kc + 0][r] = av.x;
      As[kc + 1][r] = av.y;
      As[kc + 2][r] = av.z;
      As[kc + 3][r] = av.w;
    }
    {
      int kk = tid >> 4;
      int cc = (tid & 15) << 2;
      *(float4*)&Bs[kk][cc] = *(const float4*)(B + (size_t)(k0 + kk) * M + colBase + cc);
    }
    __syncthreads();
#pragma unroll
    for (int kk = 0; kk < KT; ++kk) {
      float4 a4 = *(const float4*)&As[kk][ty << 2];
      float4 b4 = *(const float4*)&Bs[kk][tx << 2];
      float aa[4] = {a4.x, a4.y, a4.z, a4.w};
      float bb[4] = {b4.x, b4.y, b4.z, b4.w};
#pragma unroll
      for (int i = 0; i < 4; i++)
#pragma unroll
        for (int j = 0; j < 4; j++) acc[i][j] = fmaf(aa[i], bb[j], acc[i][j]);
    }
    __syncthreads();
  }
#pragma unroll
  for (int i = 0; i < 4; i++) {
    int row = rowBase + (ty << 2) + i;
    if (row < N) {
      float4 v = make_float4(acc[i][0], acc[i][1], acc[i][2], acc[i][3]);
      *(float4*)(C + (size_t)row * M + colBase + (tx << 2)) = v;
    }
  }
}

// per-(node,head) attention scores: s = <h[n,h,:], a[h,:]>
__global__ void att_scores(const float* __restrict__ h,
                           const float* __restrict__ a_src,
                           const float* __restrict__ a_dst,
                           float* __restrict__ ssrc, float* __restrict__ sdst,
                           int N, int H, int C) {
  int idx = blockIdx.x * blockDim.x + threadIdx.x;
  if (idx >= N * H) return;
  int n = idx / H, hh = idx % H;
  const float* hp = h + (size_t)n * H * C + (size_t)hh * C;
  const float* as = a_src + hh * C;
  const float* ad = a_dst + hh * C;
  float s1 = 0.f, s2 = 0.f;
  for (int c = 0; c < C; ++c) {
    float v = hp[c];
    s1 = fmaf(v, as[c], s1);
    s2 = fmaf(v, ad[c], s2);
  }
  ssrc[idx] = s1;
  sdst[idx] = s2;
}

// ---- CSR build --------------------------------------------------------------

__global__ void k_deg(const int* __restrict__ ei, int E, int N, int* __restrict__ deg) {
  int e = blockIdx.x * blockDim.x + threadIdx.x;
  if (e >= E + N) return;
  int d = (e < E) ? ei[E + e] : (e - E);
  atomicAdd(deg + d, 1);
}

// exclusive scan within each 256-thread block; bsum[block] = block total
__global__ __launch_bounds__(256) void k_scan_block(const int* __restrict__ in,
                                                    int* __restrict__ out_part,
                                                    int* __restrict__ bsum, int n) {
  int tid = threadIdx.x, lane = tid & 63, wv = tid >> 6;
  int i = blockIdx.x * 256 + tid;
  int v = (i < n) ? in[i] : 0;
  int x = v;
#pragma unroll
  for (int off = 1; off < 64; off <<= 1) {
    int y = __shfl_up(x, off);
    if (lane >= off) x += y;
  }
  __shared__ int ws[4];
  if (lane == 63) ws[wv] = x;
  __syncthreads();
  int wo = 0;
  for (int w = 0; w < wv; ++w) wo += ws[w];
  if (i < n) out_part[i] = wo + x - v;
  if (tid == 255 && bsum) bsum[blockIdx.x] = wo + x;
}

__global__ void k_scan_add(int* __restrict__ rowptr, const int* __restrict__ boff,
                           int n, int total) {
  int i = blockIdx.x * blockDim.x + threadIdx.x;
  if (i < n) rowptr[i] += boff[blockIdx.x];
  if (i == 0) rowptr[n] = total;
}

__global__ void k_fill(const int* __restrict__ ei, int E, int N,
                       const int* __restrict__ rowptr, int* __restrict__ cursor,
                       int* __restrict__ csr) {
  int e = blockIdx.x * blockDim.x + threadIdx.x;
  if (e >= E + N) return;
  int s, d;
  if (e < E) {
    s = ei[e];
    d = ei[E + e];
  } else {
    s = e - E;
    d = s;
  }
  int pos = rowptr[d] + atomicAdd(cursor + d, 1);
  csr[pos] = s;
}

// ---- fused softmax + aggregate + bias + act ---------------------------------
// One wave per dst node; lane owns VEC channels. out = sum(w*h[src])/sum(w)+b.
template <int H, int C, int VEC>
__global__ __launch_bounds__(256) void gat_aggr(
    const int* __restrict__ rowptr, const int* __restrict__ csr,
    const float* __restrict__ h, const float* __restrict__ ssrc,
    const float* __restrict__ sdst, const float* __restrict__ bias,
    float* __restrict__ out, int N, int do_relu) {
  const int HC = H * C;
  int lane = threadIdx.x & 63;
  int n = blockIdx.x * 4 + (threadIdx.x >> 6);
  if (n >= N) return;
  int c0 = lane * VEC;
  int hh = c0 / C;
  float sdst_n = sdst[n * H + hh];
  int beg = rowptr[n], end = rowptr[n + 1];
  float acc[VEC];
#pragma unroll
  for (int k = 0; k < VEC; k++) acc[k] = 0.f;
  float wsum = 0.f;
  for (int e = beg; e < end; ++e) {
    int src = csr[e];
    float sc = ssrc[src * H + hh] + sdst_n;
    sc = sc > 0.f ? sc : 0.2f * sc;
    float w = __expf(sc);
    wsum += w;
    const float* hp = h + (size_t)src * HC + c0;
#pragma unroll
    for (int k = 0; k < VEC; k++) acc[k] = fmaf(w, hp[k], acc[k]);
  }
  float inv = 1.f / wsum;  // >=1 edge per node guaranteed by self loop
  float* op = out + (size_t)n * HC + c0;
#pragma unroll
  for (int k = 0; k < VEC; k++) {
    float v = fmaf(acc[k], inv, bias[c0 + k]);
    if (do_relu) v = fmaxf(v, 0.f);
    op[k] = v;
  }
}

extern "C" void kernel_launch(void* const* d_in, const int* in_sizes, int n_in,
                              void* d_out, int out_size, void* d_ws, size_t ws_size,
                              hipStream_t stream) {
  const float* x   = (const float*)d_in[0];
  const int*   ei  = (const int*)d_in[1];
  const float* W1  = (const float*)d_in[2];
  const float* as1 = (const float*)d_in[3];
  const float* ad1 = (const float*)d_in[4];
  const float* b1  = (const float*)d_in[5];
  const float* W2  = (const float*)d_in[6];
  const float* as2 = (const float*)d_in[7];
  const float* ad2 = (const float*)d_in[8];
  const float* b2  = (const float*)d_in[9];

  const int N = in_sizes[0] / 128;  // 50000
  const int E = in_sizes[1] / 2;    // 800000
  const int ET = E + N;
  const int NB = (N + 255) / 256;   // 196 scan blocks

  float* p = (float*)d_ws;
  float* h1    = p; p += (size_t)N * 128;  // layer1 features; reused as h2
  float* ssrc1 = p; p += (size_t)N * 4;
  float* sdst1 = p; p += (size_t)N * 4;
  float* out1  = p; p += (size_t)N * 128;
  float* ssrc2 = p; p += N;
  float* sdst2 = p; p += N;
  float* h2 = h1;  // alias: h1 dead after layer1 aggregation

  int* ip = (int*)p;
  int* rowptr = ip; ip += N + 1;
  int* deg    = ip; ip += N;      // deg+cursor contiguous -> single memset
  int* cursor = ip; ip += N;
  int* bsum   = ip; ip += NB;
  int* boff   = ip; ip += NB;
  int* csr    = ip; ip += ET;

  hipMemsetAsync(deg, 0, 2 * (size_t)N * sizeof(int), stream);

  dim3 blk(256);

  // ---- CSR build (shared by both layers) ----
  k_deg<<<dim3((ET + 255) / 256), blk, 0, stream>>>(ei, E, N, deg);
  k_scan_block<<<dim3(NB), blk, 0, stream>>>(deg, rowptr, bsum, N);
  k_scan_block<<<dim3(1), blk, 0, stream>>>(bsum, boff, nullptr, NB);
  k_scan_add<<<dim3(NB), blk, 0, stream>>>(rowptr, boff, N, ET);
  k_fill<<<dim3((ET + 255) / 256), blk, 0, stream>>>(ei, E, N, rowptr, cursor, csr);

  // ---- layer 1: 128 -> 4 heads x 32, concat, +bias, ReLU ----
  gemm_k128<<<dim3((N + TS - 1) / TS, 128 / TS), blk, 0, stream>>>(x, W1, h1, N, 128);
  att_scores<<<dim3((N * 4 + 255) / 256), blk, 0, stream>>>(h1, as1, ad1, ssrc1, sdst1, N, 4, 32);
  gat_aggr<4, 32, 2><<<dim3((N + 3) / 4), blk, 0, stream>>>(
      rowptr, csr, h1, ssrc1, sdst1, b1, out1, N, 1);

  // ---- layer 2: 128 -> 1 head x 64, +bias ----
  gemm_k128<<<dim3((N + TS - 1) / TS, 1), blk, 0, stream>>>(out1, W2, h2, N, 64);
  att_scores<<<dim3((N + 255) / 256), blk, 0, stream>>>(h2, as2, ad2, ssrc2, sdst2, N, 1, 64);
  gat_aggr<1, 64, 1><<<dim3((N + 3) / 4), blk, 0, stream>>>(
      rowptr, csr, h2, ssrc2, sdst2, b2, (float*)d_out, N, 0);
}

// Round 3
// 359.653 us; speedup vs baseline: 7.0436x; 1.2531x over previous
//
#include <hip/hip_runtime.h>
#include <hip/hip_bf16.h>

// ---------------------------------------------------------------------------
// GAT 2-layer forward. N=50000, E=800000 (+N self loops).
// Round 3: bf16 feature storage (2x less gather traffic), MFMA bf16 GEMMs,
// CSR gather aggregation with fused softmax/bias/act, unroll-2 edge loop.
// ---------------------------------------------------------------------------

typedef __attribute__((ext_vector_type(8))) short bf16x8;
typedef __attribute__((ext_vector_type(4))) float f32x4;

__device__ __forceinline__ unsigned short f2bf(float f) {
  unsigned x = __float_as_uint(f);
  unsigned r = (x + 0x7fffu + ((x >> 16) & 1u)) >> 16;  // RNE
  return (unsigned short)r;
}
__device__ __forceinline__ float bf2f(unsigned short u) {
  return __uint_as_float(((unsigned)u) << 16);
}
__device__ __forceinline__ float bflo(unsigned u) {
  return __uint_as_float(u << 16);
}
__device__ __forceinline__ float bfhi(unsigned u) {
  return __uint_as_float(u & 0xffff0000u);
}

// ---- conversions ------------------------------------------------------------

// out[i] = bf16(in[i]); n multiple of 4
__global__ void cvt_bf16(const float* __restrict__ in,
                         unsigned short* __restrict__ out, int n) {
  int b = (blockIdx.x * blockDim.x + threadIdx.x) * 4;
  if (b >= n) return;
  float4 v = *(const float4*)(in + b);
  unsigned lo = (unsigned)f2bf(v.x) | ((unsigned)f2bf(v.y) << 16);
  unsigned hi = (unsigned)f2bf(v.z) | ((unsigned)f2bf(v.w) << 16);
  *(uint2*)(out + b) = make_uint2(lo, hi);
}

// W [K][M] f32 -> Wt [M][K] bf16
__global__ void cvt_w(const float* __restrict__ W, unsigned short* __restrict__ Wt,
                      int K, int M) {
  int i = blockIdx.x * blockDim.x + threadIdx.x;
  if (i >= K * M) return;
  int k = i / M, m = i % M;
  Wt[m * K + k] = f2bf(W[i]);
}

// ---- MFMA GEMM: C[N][M] bf16 = A[N][128] bf16 @ Bt[M][128]^T ---------------
// One wave per 16 rows; wave iterates col-tiles of 16. K=128 -> 4 MFMAs/tile.
__global__ __launch_bounds__(256) void gemm_mfma(
    const unsigned short* __restrict__ A, const unsigned short* __restrict__ Bt,
    unsigned short* __restrict__ C, int N, int M) {
  const int K = 128;
  int lane = threadIdx.x & 63;
  int wv = threadIdx.x >> 6;
  int row0 = blockIdx.x * 64 + wv * 16;
  if (row0 >= N) return;  // N % 16 == 0
  int r = lane & 15, quad = lane >> 4;

  bf16x8 a[4];
  const unsigned short* ap = A + (size_t)(row0 + r) * K + quad * 8;
#pragma unroll
  for (int t = 0; t < 4; ++t) a[t] = *(const bf16x8*)(ap + t * 32);

  for (int c0 = 0; c0 < M; c0 += 16) {
    f32x4 acc = {0.f, 0.f, 0.f, 0.f};
    const unsigned short* bp = Bt + (size_t)(c0 + r) * K + quad * 8;
#pragma unroll
    for (int t = 0; t < 4; ++t) {
      bf16x8 b = *(const bf16x8*)(bp + t * 32);
      acc = __builtin_amdgcn_mfma_f32_16x16x32_bf16(a[t], b, acc, 0, 0, 0);
    }
    // C/D layout: col = lane&15, row = quad*4 + i
    unsigned short* cp = C + (size_t)(row0 + quad * 4) * M + c0 + r;
#pragma unroll
    for (int i = 0; i < 4; ++i) cp[(size_t)i * M] = f2bf(acc[i]);
  }
}

// ---- attention scores (bf16 input) -----------------------------------------
__global__ void att_scores_bf(const unsigned short* __restrict__ h,
                              const float* __restrict__ a_src,
                              const float* __restrict__ a_dst,
                              float* __restrict__ ssrc, float* __restrict__ sdst,
                              int N, int H, int C) {
  int idx = blockIdx.x * blockDim.x + threadIdx.x;
  if (idx >= N * H) return;
  int n = idx / H, hh = idx % H;
  const unsigned short* hp = h + (size_t)n * H * C + (size_t)hh * C;
  const float* as = a_src + hh * C;
  const float* ad = a_dst + hh * C;
  float s1 = 0.f, s2 = 0.f;
  for (int c = 0; c < C; c += 2) {
    unsigned u = *(const unsigned*)(hp + c);
    float f0 = bflo(u), f1 = bfhi(u);
    s1 = fmaf(f0, as[c], fmaf(f1, as[c + 1], s1));
    s2 = fmaf(f0, ad[c], fmaf(f1, ad[c + 1], s2));
  }
  ssrc[idx] = s1;
  sdst[idx] = s2;
}

// ---- CSR build --------------------------------------------------------------

__global__ void k_deg(const int* __restrict__ ei, int E, int N, int* __restrict__ deg) {
  int e = blockIdx.x * blockDim.x + threadIdx.x;
  if (e >= E + N) return;
  int d = (e < E) ? ei[E + e] : (e - E);
  atomicAdd(deg + d, 1);
}

__global__ __launch_bounds__(256) void k_scan_block(const int* __restrict__ in,
                                                    int* __restrict__ out_part,
                                                    int* __restrict__ bsum, int n) {
  int tid = threadIdx.x, lane = tid & 63, wv = tid >> 6;
  int i = blockIdx.x * 256 + tid;
  int v = (i < n) ? in[i] : 0;
  int x = v;
#pragma unroll
  for (int off = 1; off < 64; off <<= 1) {
    int y = __shfl_up(x, off);
    if (lane >= off) x += y;
  }
  __shared__ int ws[4];
  if (lane == 63) ws[wv] = x;
  __syncthreads();
  int wo = 0;
  for (int w = 0; w < wv; ++w) wo += ws[w];
  if (i < n) out_part[i] = wo + x - v;
  if (tid == 255 && bsum) bsum[blockIdx.x] = wo + x;
}

__global__ void k_scan_add(int* __restrict__ rowptr, const int* __restrict__ boff,
                           int n, int total) {
  int i = blockIdx.x * blockDim.x + threadIdx.x;
  if (i < n) rowptr[i] += boff[blockIdx.x];
  if (i == 0) rowptr[n] = total;
}

__global__ void k_fill(const int* __restrict__ ei, int E, int N,
                       const int* __restrict__ rowptr, int* __restrict__ cursor,
                       int* __restrict__ csr) {
  int e = blockIdx.x * blockDim.x + threadIdx.x;
  if (e >= E + N) return;
  int s, d;
  if (e < E) {
    s = ei[e];
    d = ei[E + e];
  } else {
    s = e - E;
    d = s;
  }
  int pos = rowptr[d] + atomicAdd(cursor + d, 1);
  csr[pos] = s;
}

// ---- fused softmax + aggregate + bias + act (bf16 gather) -------------------
// One wave per dst node; lane owns VEC channels (bf16). Unroll-2 edge loop.
// OUT_BF16=1: write bf16 + ReLU (layer1). OUT_BF16=0: write f32 (layer2).
template <int H, int C, int VEC, int OUT_BF16>
__global__ __launch_bounds__(256) void gat_aggr_bf(
    const int* __restrict__ rowptr, const int* __restrict__ csr,
    const unsigned short* __restrict__ h, const float* __restrict__ ssrc,
    const float* __restrict__ sdst, const float* __restrict__ bias,
    void* __restrict__ outv, int N) {
  const int HC = H * C;
  int lane = threadIdx.x & 63;
  int n = blockIdx.x * 4 + (threadIdx.x >> 6);
  if (n >= N) return;
  int c0 = lane * VEC;
  int hh = c0 / C;
  float sdst_n = sdst[n * H + hh];
  int beg = rowptr[n], end = rowptr[n + 1];
  float acc0 = 0.f, acc1 = 0.f, wsum = 0.f;
  int e = beg;
  for (; e + 2 <= end; e += 2) {
    int s0 = csr[e], s1 = csr[e + 1];
    float sc0 = ssrc[s0 * H + hh] + sdst_n;
    float sc1 = ssrc[s1 * H + hh] + sdst_n;
    sc0 = sc0 > 0.f ? sc0 : 0.2f * sc0;
    sc1 = sc1 > 0.f ? sc1 : 0.2f * sc1;
    float w0 = __expf(sc0), w1 = __expf(sc1);
    if (VEC == 2) {
      unsigned u0 = *(const unsigned*)(h + (size_t)s0 * HC + c0);
      unsigned u1 = *(const unsigned*)(h + (size_t)s1 * HC + c0);
      acc0 = fmaf(w0, bflo(u0), acc0);
      acc1 = fmaf(w0, bfhi(u0), acc1);
      acc0 = fmaf(w1, bflo(u1), acc0);
      acc1 = fmaf(w1, bfhi(u1), acc1);
    } else {
      acc0 = fmaf(w0, bf2f(h[(size_t)s0 * HC + c0]), acc0);
      acc0 = fmaf(w1, bf2f(h[(size_t)s1 * HC + c0]), acc0);
    }
    wsum += w0 + w1;
  }
  if (e < end) {
    int s0 = csr[e];
    float sc0 = ssrc[s0 * H + hh] + sdst_n;
    sc0 = sc0 > 0.f ? sc0 : 0.2f * sc0;
    float w0 = __expf(sc0);
    if (VEC == 2) {
      unsigned u0 = *(const unsigned*)(h + (size_t)s0 * HC + c0);
      acc0 = fmaf(w0, bflo(u0), acc0);
      acc1 = fmaf(w0, bfhi(u0), acc1);
    } else {
      acc0 = fmaf(w0, bf2f(h[(size_t)s0 * HC + c0]), acc0);
    }
    wsum += w0;
  }
  float inv = 1.f / wsum;  // self-loop guarantees wsum > 0
  if (OUT_BF16) {
    float v0 = fmaf(acc0, inv, bias[c0]);
    float v1 = fmaf(acc1, inv, bias[c0 + 1]);
    v0 = fmaxf(v0, 0.f);
    v1 = fmaxf(v1, 0.f);
    ((unsigned*)outv)[(size_t)n * (HC / 2) + lane] =
        (unsigned)f2bf(v0) | ((unsigned)f2bf(v1) << 16);
  } else {
    float v = fmaf(acc0, inv, bias[c0]);
    ((float*)outv)[(size_t)n * HC + c0] = v;
  }
}

extern "C" void kernel_launch(void* const* d_in, const int* in_sizes, int n_in,
                              void* d_out, int out_size, void* d_ws, size_t ws_size,
                              hipStream_t stream) {
  const float* x   = (const float*)d_in[0];
  const int*   ei  = (const int*)d_in[1];
  const float* W1  = (const float*)d_in[2];
  const float* as1 = (const float*)d_in[3];
  const float* ad1 = (const float*)d_in[4];
  const float* b1  = (const float*)d_in[5];
  const float* W2  = (const float*)d_in[6];
  const float* as2 = (const float*)d_in[7];
  const float* ad2 = (const float*)d_in[8];
  const float* b2  = (const float*)d_in[9];

  const int N = in_sizes[0] / 128;  // 50000
  const int E = in_sizes[1] / 2;    // 800000
  const int ET = E + N;
  const int NB = (N + 255) / 256;

  char* pc = (char*)d_ws;
  auto alloc = [&](size_t bytes) -> void* {
    void* r = (void*)pc;
    pc += (bytes + 255) & ~(size_t)255;
    return r;
  };
  unsigned short* xb    = (unsigned short*)alloc((size_t)N * 128 * 2);
  unsigned short* h1b   = (unsigned short*)alloc((size_t)N * 128 * 2);  // reused as h2b
  unsigned short* out1b = (unsigned short*)alloc((size_t)N * 128 * 2);
  unsigned short* W1t   = (unsigned short*)alloc(128 * 128 * 2);
  unsigned short* W2t   = (unsigned short*)alloc(64 * 128 * 2);
  float* ssrc1 = (float*)alloc((size_t)N * 4 * 4);
  float* sdst1 = (float*)alloc((size_t)N * 4 * 4);
  float* ssrc2 = (float*)alloc((size_t)N * 4);
  float* sdst2 = (float*)alloc((size_t)N * 4);
  int* rowptr = (int*)alloc((size_t)(N + 1) * 4);
  int* deg    = (int*)alloc((size_t)N * 4);  // deg+cursor contiguous
  int* cursor = (int*)alloc((size_t)N * 4);
  int* bsum   = (int*)alloc((size_t)NB * 4);
  int* boff   = (int*)alloc((size_t)NB * 4);
  int* csr    = (int*)alloc((size_t)ET * 4);
  unsigned short* h2b = h1b;  // alias: h1b dead after layer-1 aggregation

  hipMemsetAsync(deg, 0, 2 * (size_t)N * sizeof(int) + 256, stream);

  dim3 blk(256);

  // ---- CSR build ----
  k_deg<<<dim3((ET + 255) / 256), blk, 0, stream>>>(ei, E, N, deg);
  k_scan_block<<<dim3(NB), blk, 0, stream>>>(deg, rowptr, bsum, N);
  k_scan_block<<<dim3(1), blk, 0, stream>>>(bsum, boff, nullptr, NB);
  k_scan_add<<<dim3(NB), blk, 0, stream>>>(rowptr, boff, N, ET);
  k_fill<<<dim3((ET + 255) / 256), blk, 0, stream>>>(ei, E, N, rowptr, cursor, csr);

  // ---- conversions ----
  cvt_bf16<<<dim3((N * 128 / 4 + 255) / 256), blk, 0, stream>>>(x, xb, N * 128);
  cvt_w<<<dim3((128 * 128 + 255) / 256), blk, 0, stream>>>(W1, W1t, 128, 128);
  cvt_w<<<dim3((128 * 64 + 255) / 256), blk, 0, stream>>>(W2, W2t, 128, 64);

  // ---- layer 1: 128 -> 4 heads x 32, concat, +bias, ReLU ----
  gemm_mfma<<<dim3((N + 63) / 64), blk, 0, stream>>>(xb, W1t, h1b, N, 128);
  att_scores_bf<<<dim3((N * 4 + 255) / 256), blk, 0, stream>>>(h1b, as1, ad1, ssrc1, sdst1, N, 4, 32);
  gat_aggr_bf<4, 32, 2, 1><<<dim3((N + 3) / 4), blk, 0, stream>>>(
      rowptr, csr, h1b, ssrc1, sdst1, b1, out1b, N);

  // ---- layer 2: 128 -> 1 head x 64, +bias ----
  gemm_mfma<<<dim3((N + 63) / 64), blk, 0, stream>>>(out1b, W2t, h2b, N, 64);
  att_scores_bf<<<dim3((N + 255) / 256), blk, 0, stream>>>(h2b, as2, ad2, ssrc2, sdst2, N, 1, 64);
  gat_aggr_bf<1, 64, 1, 0><<<dim3((N + 3) / 4), blk, 0, stream>>>(
      rowptr, csr, h2b, ssrc2, sdst2, b2, d_out, N);
}

// Round 6
// 327.429 us; speedup vs baseline: 7.7368x; 1.0984x over previous
//
#include <hip/hip_runtime.h>
#include <hip/hip_bf16.h>

// ---------------------------------------------------------------------------
// GAT 2-layer forward. N=50000, E=800000 (+N self loops).
// Round 6: = round 5 with the cursor-memset fix (memset must cover the
// 256B-padded deg+cursor region; 0xAA-poisoned cursor tails caused the R5
// OOB crash in k_fill). Precomputed per-(edge,head) softmax weights;
// aggregator is pure gather+FMA, L lanes/edge, direct group-uniform csr/ew
// loads, 2-deep pipeline. bf16 features, MFMA GEMMs.
// ---------------------------------------------------------------------------

typedef __attribute__((ext_vector_type(8))) short bf16x8;
typedef __attribute__((ext_vector_type(4))) float f32x4;

__device__ __forceinline__ unsigned short f2bf(float f) {
  unsigned x = __float_as_uint(f);
  unsigned r = (x + 0x7fffu + ((x >> 16) & 1u)) >> 16;  // RNE
  return (unsigned short)r;
}
__device__ __forceinline__ float bflo(unsigned u) {
  return __uint_as_float(u << 16);
}
__device__ __forceinline__ float bfhi(unsigned u) {
  return __uint_as_float(u & 0xffff0000u);
}

// ---- weight conversions: W1[128][128] + W2[128][64] -> bf16 transposed -----
__global__ void cvt_w2(const float* __restrict__ W1, unsigned short* __restrict__ W1t,
                       const float* __restrict__ W2, unsigned short* __restrict__ W2t) {
  int i = blockIdx.x * blockDim.x + threadIdx.x;
  if (i < 128 * 128) {
    int k = i >> 7, m = i & 127;
    W1t[m * 128 + k] = f2bf(W1[i]);
  } else if (i < 128 * 128 + 128 * 64) {
    int j = i - 128 * 128;
    int k = j / 64, m = j % 64;
    W2t[m * 128 + k] = f2bf(W2[j]);
  }
}

// ---- MFMA GEMM: C[N][M] bf16 = A[N][128] @ Bt[M][128]^T --------------------
// AF32: A is f32 (converted to bf16 in-register). One wave per 16 rows.
template <int AF32>
__global__ __launch_bounds__(256) void gemm_mfma(
    const void* __restrict__ Av, const unsigned short* __restrict__ Bt,
    unsigned short* __restrict__ C, int N, int M) {
  const int K = 128;
  int lane = threadIdx.x & 63;
  int wv = threadIdx.x >> 6;
  int row0 = blockIdx.x * 64 + wv * 16;
  if (row0 >= N) return;  // N % 16 == 0
  int r = lane & 15, quad = lane >> 4;

  bf16x8 a[4];
  if (AF32) {
    const float* ap = (const float*)Av + (size_t)(row0 + r) * K + quad * 8;
#pragma unroll
    for (int t = 0; t < 4; ++t) {
      float4 lo = *(const float4*)(ap + t * 32);
      float4 hi = *(const float4*)(ap + t * 32 + 4);
      a[t][0] = (short)f2bf(lo.x); a[t][1] = (short)f2bf(lo.y);
      a[t][2] = (short)f2bf(lo.z); a[t][3] = (short)f2bf(lo.w);
      a[t][4] = (short)f2bf(hi.x); a[t][5] = (short)f2bf(hi.y);
      a[t][6] = (short)f2bf(hi.z); a[t][7] = (short)f2bf(hi.w);
    }
  } else {
    const unsigned short* ap = (const unsigned short*)Av + (size_t)(row0 + r) * K + quad * 8;
#pragma unroll
    for (int t = 0; t < 4; ++t) a[t] = *(const bf16x8*)(ap + t * 32);
  }

  for (int c0 = 0; c0 < M; c0 += 16) {
    f32x4 acc = {0.f, 0.f, 0.f, 0.f};
    const unsigned short* bp = Bt + (size_t)(c0 + r) * K + quad * 8;
#pragma unroll
    for (int t = 0; t < 4; ++t) {
      bf16x8 b = *(const bf16x8*)(bp + t * 32);
      acc = __builtin_amdgcn_mfma_f32_16x16x32_bf16(a[t], b, acc, 0, 0, 0);
    }
    unsigned short* cp = C + (size_t)(row0 + quad * 4) * M + c0 + r;
#pragma unroll
    for (int i = 0; i < 4; ++i) cp[(size_t)i * M] = f2bf(acc[i]);
  }
}

// ---- attention scores (bf16 input) -----------------------------------------
__global__ void att_scores_bf(const unsigned short* __restrict__ h,
                              const float* __restrict__ a_src,
                              const float* __restrict__ a_dst,
                              float* __restrict__ ssrc, float* __restrict__ sdst,
                              int N, int H, int C) {
  int idx = blockIdx.x * blockDim.x + threadIdx.x;
  if (idx >= N * H) return;
  int n = idx / H, hh = idx % H;
  const unsigned short* hp = h + (size_t)n * H * C + (size_t)hh * C;
  const float* as = a_src + hh * C;
  const float* ad = a_dst + hh * C;
  float s1 = 0.f, s2 = 0.f;
  for (int c = 0; c < C; c += 2) {
    unsigned u = *(const unsigned*)(hp + c);
    float f0 = bflo(u), f1 = bfhi(u);
    s1 = fmaf(f0, as[c], fmaf(f1, as[c + 1], s1));
    s2 = fmaf(f0, ad[c], fmaf(f1, ad[c + 1], s2));
  }
  ssrc[idx] = s1;
  sdst[idx] = s2;
}

// ---- CSR build --------------------------------------------------------------

__global__ void k_deg(const int* __restrict__ ei, int E, int N, int* __restrict__ deg) {
  int e = blockIdx.x * blockDim.x + threadIdx.x;
  if (e >= E + N) return;
  int d = (e < E) ? ei[E + e] : (e - E);
  atomicAdd(deg + d, 1);
}

__global__ __launch_bounds__(256) void k_scan_block(const int* __restrict__ in,
                                                    int* __restrict__ out_part,
                                                    int* __restrict__ bsum, int n) {
  int tid = threadIdx.x, lane = tid & 63, wv = tid >> 6;
  int i = blockIdx.x * 256 + tid;
  int v = (i < n) ? in[i] : 0;
  int x = v;
#pragma unroll
  for (int off = 1; off < 64; off <<= 1) {
    int y = __shfl_up(x, off);
    if (lane >= off) x += y;
  }
  __shared__ int ws[4];
  if (lane == 63) ws[wv] = x;
  __syncthreads();
  int wo = 0;
  for (int w = 0; w < wv; ++w) wo += ws[w];
  if (i < n) out_part[i] = wo + x - v;
  if (tid == 255 && bsum) bsum[blockIdx.x] = wo + x;
}

__global__ void k_scan_add(int* __restrict__ rowptr, const int* __restrict__ boff,
                           int n, int total) {
  int i = blockIdx.x * blockDim.x + threadIdx.x;
  if (i < n) rowptr[i] += boff[blockIdx.x];
  if (i == 0) rowptr[n] = total;
}

__global__ void k_fill(const int* __restrict__ ei, int E, int N,
                       const int* __restrict__ rowptr, int* __restrict__ cursor,
                       int* __restrict__ csr, int* __restrict__ csrd) {
  int e = blockIdx.x * blockDim.x + threadIdx.x;
  if (e >= E + N) return;
  int s, d;
  if (e < E) {
    s = ei[e];
    d = ei[E + e];
  } else {
    s = e - E;
    d = s;
  }
  int pos = rowptr[d] + atomicAdd(cursor + d, 1);
  csr[pos] = s;
  csrd[pos] = d;
}

// ---- per-(edge,head) softmax weights, coalesced over CSR slots --------------
template <int H>
__global__ void k_weights(const int* __restrict__ csr, const int* __restrict__ csrd,
                          int ET, const float* __restrict__ ssrc,
                          const float* __restrict__ sdst, float* __restrict__ ew) {
  int i = blockIdx.x * blockDim.x + threadIdx.x;
  if (i >= ET) return;
  int s = csr[i], d = csrd[i];
  if (H == 4) {
    float4 a = *(const float4*)(ssrc + (size_t)s * 4);
    float4 b = *(const float4*)(sdst + (size_t)d * 4);
    float4 w;
    float sc;
    sc = a.x + b.x; sc = sc > 0.f ? sc : 0.2f * sc; w.x = __expf(sc);
    sc = a.y + b.y; sc = sc > 0.f ? sc : 0.2f * sc; w.y = __expf(sc);
    sc = a.z + b.z; sc = sc > 0.f ? sc : 0.2f * sc; w.z = __expf(sc);
    sc = a.w + b.w; sc = sc > 0.f ? sc : 0.2f * sc; w.w = __expf(sc);
    *(float4*)(ew + (size_t)i * 4) = w;
  } else {
    float sc = ssrc[s] + sdst[d];
    sc = sc > 0.f ? sc : 0.2f * sc;
    ew[i] = __expf(sc);
  }
}

// ---- aggregator: out[n] = (sum_e w_e * h[src_e]) / (sum_e w_e) + bias -------
// One wave per dst node. L lanes per edge (4 bf16 ch each); G=64/L edge
// groups per wave. Group g handles CSR slots beg+g, beg+g+G, ... with direct
// (group-uniform-address) csr/ew loads; manual 2-deep load pipeline.
// Cross-group combine via reconvergent shfl_xor butterfly at the end.
template <int H, int C, int L, int OUT_BF16>
__global__ __launch_bounds__(256) void gat_aggr3(
    const int* __restrict__ rowptr, const int* __restrict__ csr,
    const float* __restrict__ ew, const unsigned short* __restrict__ h,
    const float* __restrict__ bias, void* __restrict__ outv, int N) {
  const int HC = H * C;
  const int G = 64 / L;  // edge groups per wave
  int lane = threadIdx.x & 63;
  int n = blockIdx.x * 4 + (threadIdx.x >> 6);
  if (n >= N) return;
  int l = lane & (L - 1);
  int g = lane / L;
  int c0 = l * 4;
  int hh = c0 / C;
  int beg = rowptr[n];
  int cnt = rowptr[n + 1] - beg;
  float a0 = 0.f, a1 = 0.f, a2 = 0.f, a3 = 0.f, ws = 0.f;

  int j = g;
  for (; j + G < cnt; j += 2 * G) {
    int i0 = beg + j, i1 = beg + j + G;
    int s0 = csr[i0];
    int s1 = csr[i1];
    float w0 = ew[(size_t)i0 * H + hh];
    float w1 = ew[(size_t)i1 * H + hh];
    uint2 u0 = *(const uint2*)(h + (size_t)s0 * HC + c0);
    uint2 u1 = *(const uint2*)(h + (size_t)s1 * HC + c0);
    a0 = fmaf(w0, bflo(u0.x), a0);
    a1 = fmaf(w0, bfhi(u0.x), a1);
    a2 = fmaf(w0, bflo(u0.y), a2);
    a3 = fmaf(w0, bfhi(u0.y), a3);
    a0 = fmaf(w1, bflo(u1.x), a0);
    a1 = fmaf(w1, bfhi(u1.x), a1);
    a2 = fmaf(w1, bflo(u1.y), a2);
    a3 = fmaf(w1, bfhi(u1.y), a3);
    ws += w0 + w1;
  }
  if (j < cnt) {  // at most one group-iteration remains
    int i0 = beg + j;
    int s0 = csr[i0];
    float w0 = ew[(size_t)i0 * H + hh];
    uint2 u0 = *(const uint2*)(h + (size_t)s0 * HC + c0);
    a0 = fmaf(w0, bflo(u0.x), a0);
    a1 = fmaf(w0, bfhi(u0.x), a1);
    a2 = fmaf(w0, bflo(u0.y), a2);
    a3 = fmaf(w0, bfhi(u0.y), a3);
    ws += w0;
  }
#pragma unroll
  for (int off = L; off < 64; off <<= 1) {
    a0 += __shfl_xor(a0, off, 64);
    a1 += __shfl_xor(a1, off, 64);
    a2 += __shfl_xor(a2, off, 64);
    a3 += __shfl_xor(a3, off, 64);
    ws += __shfl_xor(ws, off, 64);
  }
  if (lane < L) {
    float inv = 1.f / ws;  // self-loop guarantees ws > 0
    float v0 = fmaf(a0, inv, bias[c0 + 0]);
    float v1 = fmaf(a1, inv, bias[c0 + 1]);
    float v2 = fmaf(a2, inv, bias[c0 + 2]);
    float v3 = fmaf(a3, inv, bias[c0 + 3]);
    if (OUT_BF16) {
      v0 = fmaxf(v0, 0.f); v1 = fmaxf(v1, 0.f);
      v2 = fmaxf(v2, 0.f); v3 = fmaxf(v3, 0.f);
      unsigned lo = (unsigned)f2bf(v0) | ((unsigned)f2bf(v1) << 16);
      unsigned hi = (unsigned)f2bf(v2) | ((unsigned)f2bf(v3) << 16);
      ((uint2*)outv)[(size_t)n * (HC / 4) + l] = make_uint2(lo, hi);
    } else {
      ((float4*)outv)[(size_t)n * (HC / 4) + l] = make_float4(v0, v1, v2, v3);
    }
  }
}

extern "C" void kernel_launch(void* const* d_in, const int* in_sizes, int n_in,
                              void* d_out, int out_size, void* d_ws, size_t ws_size,
                              hipStream_t stream) {
  const float* x   = (const float*)d_in[0];
  const int*   ei  = (const int*)d_in[1];
  const float* W1  = (const float*)d_in[2];
  const float* as1 = (const float*)d_in[3];
  const float* ad1 = (const float*)d_in[4];
  const float* b1  = (const float*)d_in[5];
  const float* W2  = (const float*)d_in[6];
  const float* as2 = (const float*)d_in[7];
  const float* ad2 = (const float*)d_in[8];
  const float* b2  = (const float*)d_in[9];

  const int N = in_sizes[0] / 128;  // 50000
  const int E = in_sizes[1] / 2;    // 800000
  const int ET = E + N;
  const int NB = (N + 255) / 256;

  char* pc = (char*)d_ws;
  auto alloc = [&](size_t bytes) -> void* {
    void* r = (void*)pc;
    pc += (bytes + 255) & ~(size_t)255;
    return r;
  };
  unsigned short* h1b   = (unsigned short*)alloc((size_t)N * 128 * 2);  // reused as h2b
  unsigned short* out1b = (unsigned short*)alloc((size_t)N * 128 * 2);
  unsigned short* W1t   = (unsigned short*)alloc(128 * 128 * 2);
  unsigned short* W2t   = (unsigned short*)alloc(64 * 128 * 2);
  float* ssrc1 = (float*)alloc((size_t)N * 4 * 4);
  float* sdst1 = (float*)alloc((size_t)N * 4 * 4);
  float* ssrc2 = (float*)alloc((size_t)N * 4);
  float* sdst2 = (float*)alloc((size_t)N * 4);
  int* rowptr = (int*)alloc((size_t)(N + 1) * 4);
  int* deg    = (int*)alloc((size_t)N * 4);  // deg+cursor adjacent padded allocs
  int* cursor = (int*)alloc((size_t)N * 4);
  int* bsum   = (int*)alloc((size_t)NB * 4);
  int* boff   = (int*)alloc((size_t)NB * 4);
  int* csr    = (int*)alloc((size_t)ET * 4);
  int* csrd   = (int*)alloc((size_t)ET * 4);
  float* ew1  = (float*)alloc((size_t)ET * 4 * 4);
  float* ew2  = (float*)alloc((size_t)ET * 4);
  unsigned short* h2b = h1b;  // alias: h1b dead after layer-1 aggregation

  // R5 bug fix: must cover the PADDED deg+cursor region ((char*)bsum - (char*)deg),
  // not 2*N*4 — alloc pads to 256B, poisoned cursor tail caused OOB in k_fill.
  hipMemsetAsync(deg, 0, (size_t)((char*)bsum - (char*)deg), stream);

  dim3 blk(256);

  // ---- CSR build (shared by both layers) ----
  k_deg<<<dim3((ET + 255) / 256), blk, 0, stream>>>(ei, E, N, deg);
  k_scan_block<<<dim3(NB), blk, 0, stream>>>(deg, rowptr, bsum, N);
  k_scan_block<<<dim3(1), blk, 0, stream>>>(bsum, boff, nullptr, NB);
  k_scan_add<<<dim3(NB), blk, 0, stream>>>(rowptr, boff, N, ET);
  k_fill<<<dim3((ET + 255) / 256), blk, 0, stream>>>(ei, E, N, rowptr, cursor, csr, csrd);

  cvt_w2<<<dim3((128 * 128 + 128 * 64 + 255) / 256), blk, 0, stream>>>(W1, W1t, W2, W2t);

  // ---- layer 1: 128 -> 4 heads x 32, concat, +bias, ReLU ----
  gemm_mfma<1><<<dim3((N + 63) / 64), blk, 0, stream>>>(x, W1t, h1b, N, 128);
  att_scores_bf<<<dim3((N * 4 + 255) / 256), blk, 0, stream>>>(h1b, as1, ad1, ssrc1, sdst1, N, 4, 32);
  k_weights<4><<<dim3((ET + 255) / 256), blk, 0, stream>>>(csr, csrd, ET, ssrc1, sdst1, ew1);
  gat_aggr3<4, 32, 32, 1><<<dim3((N + 3) / 4), blk, 0, stream>>>(
      rowptr, csr, ew1, h1b, b1, out1b, N);

  // ---- layer 2: 128 -> 1 head x 64, +bias ----
  gemm_mfma<0><<<dim3((N + 63) / 64), blk, 0, stream>>>(out1b, W2t, h2b, N, 64);
  att_scores_bf<<<dim3((N + 255) / 256), blk, 0, stream>>>(h2b, as2, ad2, ssrc2, sdst2, N, 1, 64);
  k_weights<1><<<dim3((ET + 255) / 256), blk, 0, stream>>>(csr, csrd, ET, ssrc2, sdst2, ew2);
  gat_aggr3<1, 64, 16, 0><<<dim3((N + 3) / 4), blk, 0, stream>>>(
      rowptr, csr, ew2, h2b, b2, d_out, N);
}